// Round 1
// baseline (7202.869 us; speedup 1.0000x reference)
//
#include <hip/hip_runtime.h>
#include <hip/hip_bf16.h>

#define S_LEN 60
#define BATCH 256
#define EMB   300
#define HID   512
#define DMLP  1024
#define NROW  (2*S_LEN*BATCH)   /* 30720 rows (both sentences) */
#define RPS   (S_LEN*BATCH)     /* 15360 rows per sentence */

static __device__ __forceinline__ float sigf(float x){
  return 1.0f/(1.0f+__expf(-x));
}
static __device__ __forceinline__ float tanh_fast(float x){
  x = fminf(fmaxf(x,-40.0f),40.0f);
  float a = __expf(2.0f*x);
  return (a-1.0f)/(a+1.0f);
}

// ---------------------------------------------------------------------------
// K1: embedding gather + projection GEMM.  C[r,n] = emb[tok(r)]·projW[n,:] + b
// r in [0,30720), n in [0,300). BM=64, BN=64 (guarded), BK=32, 4x4 microtile.
// ---------------------------------------------------------------------------
__global__ __launch_bounds__(256) void k_embed_proj(
    const float* __restrict__ embed, const float* __restrict__ projW,
    const float* __restrict__ projb, const int* __restrict__ s1,
    const int* __restrict__ s2, float* __restrict__ P)
{
  __shared__ float As[64][33];
  __shared__ float Bs[64][33];
  __shared__ int stok[64];
  const int m0 = blockIdx.x * 64;
  const int n0 = blockIdx.y * 64;
  const int tid = threadIdx.x;
  if (tid < 64){
    int r = m0 + tid;
    stok[tid] = (r < RPS) ? s1[r] : s2[r - RPS];
  }
  __syncthreads();
  const int tx = tid & 15, ty = tid >> 4;
  float acc[4][4];
  #pragma unroll
  for (int a=0;a<4;a++)
    #pragma unroll
    for (int b=0;b<4;b++) acc[a][b]=0.0f;

  for (int k0=0; k0<EMB; k0+=32){
    #pragma unroll
    for (int i=0;i<8;i++){
      int e = tid + i*256;
      int rl = e>>5, kl = e&31, kk = k0+kl;
      As[rl][kl] = (kk<EMB) ? embed[(size_t)stok[rl]*EMB + kk] : 0.0f;
      int nn = n0 + rl;
      Bs[rl][kl] = (nn<EMB && kk<EMB) ? projW[(size_t)nn*EMB + kk] : 0.0f;
    }
    __syncthreads();
    #pragma unroll
    for (int kk=0;kk<32;kk++){
      float a[4], w[4];
      #pragma unroll
      for (int rl=0;rl<4;rl++) a[rl] = As[ty*4+rl][kk];
      #pragma unroll
      for (int cj=0;cj<4;cj++) w[cj] = Bs[cj*16+tx][kk];
      #pragma unroll
      for (int rl=0;rl<4;rl++)
        #pragma unroll
        for (int cj=0;cj<4;cj++) acc[rl][cj] = fmaf(a[rl], w[cj], acc[rl][cj]);
    }
    __syncthreads();
  }
  #pragma unroll
  for (int rl=0;rl<4;rl++){
    int r = m0 + ty*4 + rl;
    #pragma unroll
    for (int cj=0;cj<4;cj++){
      int n = n0 + cj*16 + tx;
      if (n < EMB) P[(size_t)r*EMB + n] = acc[rl][cj] + projb[n];
    }
  }
}

// ---------------------------------------------------------------------------
// K2: BN partial sums per (sent, rowblock of 256, channel). Coalesced rows.
// ---------------------------------------------------------------------------
__global__ __launch_bounds__(320) void k_bn_partial(const float* __restrict__ P,
    float* __restrict__ ps, float* __restrict__ psq)
{
  const int rb = blockIdx.x, sent = blockIdx.y, t = threadIdx.x;
  if (t >= EMB) return;
  const float* base = P + ((size_t)sent*RPS + (size_t)rb*256)*EMB;
  float s=0.0f, q=0.0f;
  for (int r=0;r<256;r++){
    float v = base[(size_t)r*EMB + t];
    s += v; q = fmaf(v,v,q);
  }
  ps [(size_t)(sent*60+rb)*EMB + t] = s;
  psq[(size_t)(sent*60+rb)*EMB + t] = q;
}

// K2b: finalize per-sentence scale/shift
__global__ __launch_bounds__(320) void k_bn_final(const float* __restrict__ ps,
    const float* __restrict__ psq, const float* __restrict__ g,
    const float* __restrict__ b, float* __restrict__ scale, float* __restrict__ shift)
{
  const int sent = blockIdx.x, t = threadIdx.x;
  if (t >= EMB) return;
  float s=0.0f, q=0.0f;
  for (int i=0;i<60;i++){
    s += ps [(size_t)(sent*60+i)*EMB + t];
    q += psq[(size_t)(sent*60+i)*EMB + t];
  }
  float mean = s * (1.0f/15360.0f);
  float var  = q * (1.0f/15360.0f) - mean*mean;
  float sc = g[t] * rsqrtf(var + 1e-5f);
  scale[sent*EMB+t] = sc;
  shift[sent*EMB+t] = b[t] - mean*sc;
}

// K3: apply BN in place over P
__global__ __launch_bounds__(256) void k_bn_apply(float* __restrict__ P,
    const float* __restrict__ scale, const float* __restrict__ shift)
{
  size_t total = (size_t)NROW*EMB;
  for (size_t i = (size_t)blockIdx.x*blockDim.x + threadIdx.x; i < total;
       i += (size_t)gridDim.x*blockDim.x){
    int ch = (int)(i % EMB);
    int sent = (i >= (size_t)RPS*EMB) ? 1 : 0;
    P[i] = fmaf(P[i], scale[sent*EMB+ch], shift[sent*EMB+ch]);
  }
}

// ---------------------------------------------------------------------------
// K4: one LSTM step for both sentences (M=512 rows). Fused K=300(+512) GEMM
// with 4 gate accumulators per (row,j) cell. BM=32 rows, BJ=16 cols, BK=32.
// grid (16, 32) = 512 blocks.
// ---------------------------------------------------------------------------
__global__ __launch_bounds__(256) void k_lstm_step(
    const float* __restrict__ P, const float* __restrict__ Wih,
    const float* __restrict__ Whh, const float* __restrict__ bih,
    const float* __restrict__ bhh, const float* __restrict__ h_in,
    float* __restrict__ h_out, float* __restrict__ cst,
    __hip_bfloat16* __restrict__ Hout, int t)
{
  __shared__ float As[32][33];
  __shared__ float Ws[64][33];
  const int m0 = blockIdx.x * 32;
  const int j0 = blockIdx.y * 16;
  const int tid = threadIdx.x;
  const int tx = tid & 15, ty = tid >> 4;
  float acc[2][4];
  #pragma unroll
  for (int r=0;r<2;r++)
    #pragma unroll
    for (int g=0;g<4;g++) acc[r][g]=0.0f;

  // phase 1: x_t @ Wih^T (K = 300)
  for (int k0=0; k0<EMB; k0+=32){
    #pragma unroll
    for (int i=0;i<4;i++){
      int e = tid + i*256;
      int rl = e>>5, kl = e&31, kk = k0+kl;
      int r = m0 + rl;
      int sent = r>>8, b = r&255;
      As[rl][kl] = (kk<EMB) ? P[((size_t)(sent*S_LEN+t)*BATCH + b)*EMB + kk] : 0.0f;
    }
    #pragma unroll
    for (int i=0;i<8;i++){
      int e = tid + i*256;
      int wr = e>>5, kl = e&31, kk = k0+kl;
      int g = wr>>4, jl = wr&15;
      Ws[wr][kl] = (kk<EMB) ? Wih[(size_t)(g*HID + j0 + jl)*EMB + kk] : 0.0f;
    }
    __syncthreads();
    #pragma unroll
    for (int kk=0;kk<32;kk++){
      float a0 = As[ty*2+0][kk];
      float a1 = As[ty*2+1][kk];
      #pragma unroll
      for (int g=0;g<4;g++){
        float w = Ws[g*16+tx][kk];
        acc[0][g] = fmaf(a0,w,acc[0][g]);
        acc[1][g] = fmaf(a1,w,acc[1][g]);
      }
    }
    __syncthreads();
  }
  // phase 2: h_{t-1} @ Whh^T (K = 512)
  for (int k0=0; k0<HID; k0+=32){
    #pragma unroll
    for (int i=0;i<4;i++){
      int e = tid + i*256;
      int rl = e>>5, kl = e&31;
      As[rl][kl] = h_in[(size_t)(m0+rl)*HID + k0 + kl];
    }
    #pragma unroll
    for (int i=0;i<8;i++){
      int e = tid + i*256;
      int wr = e>>5, kl = e&31;
      int g = wr>>4, jl = wr&15;
      Ws[wr][kl] = Whh[(size_t)(g*HID + j0 + jl)*HID + k0 + kl];
    }
    __syncthreads();
    #pragma unroll
    for (int kk=0;kk<32;kk++){
      float a0 = As[ty*2+0][kk];
      float a1 = As[ty*2+1][kk];
      #pragma unroll
      for (int g=0;g<4;g++){
        float w = Ws[g*16+tx][kk];
        acc[0][g] = fmaf(a0,w,acc[0][g]);
        acc[1][g] = fmaf(a1,w,acc[1][g]);
      }
    }
    __syncthreads();
  }

  const int j = j0 + tx;
  float zb[4];
  #pragma unroll
  for (int g=0;g<4;g++) zb[g] = bih[g*HID+j] + bhh[g*HID+j];
  #pragma unroll
  for (int rl=0;rl<2;rl++){
    int r = m0 + ty*2 + rl;
    float zi = acc[rl][0]+zb[0];
    float zf = acc[rl][1]+zb[1];
    float zg = acc[rl][2]+zb[2];
    float zo = acc[rl][3]+zb[3];
    size_t ci = (size_t)r*HID + j;
    float cn = fmaf(sigf(zf), cst[ci], sigf(zi)*tanh_fast(zg));
    cst[ci] = cn;
    float hn = sigf(zo)*tanh_fast(cn);
    h_out[ci] = hn;
    int sent = r>>8, b = r&255;
    Hout[((size_t)(sent*S_LEN+t)*BATCH + b)*HID + j] = __float2bfloat16(hn);
  }
}

// ---------------------------------------------------------------------------
// K5: fused pairwise-L2-distance + 15x15 min-pool, one block per batch elem.
// h1,h2 staged as bf16 pairs in LDS (padded stride vs bank conflicts).
// Thread t<225 owns pooled cell (gi,gj) = 4x4 distance tile -> min16.
// ---------------------------------------------------------------------------
#define SDU 258
__global__ __launch_bounds__(256) void k_dist_pool(
    const __hip_bfloat16* __restrict__ Hout, float* __restrict__ pooled)
{
  __shared__ unsigned int h1s[S_LEN*SDU];
  __shared__ unsigned int h2s[S_LEN*SDU];
  __shared__ float n1s[S_LEN], n2s[S_LEN];
  const int b = blockIdx.x, tid = threadIdx.x;
  const unsigned int* H = (const unsigned int*)Hout;  // 256 uints per row
  for (int e=tid; e<S_LEN*256; e+=256){
    int row = e>>8, cu = e&255;
    h1s[row*SDU+cu] = H[((size_t)(0*S_LEN+row)*BATCH + b)*256 + cu];
    h2s[row*SDU+cu] = H[((size_t)(1*S_LEN+row)*BATCH + b)*256 + cu];
  }
  __syncthreads();
  if (tid < S_LEN){
    const unsigned int* rp = &h1s[tid*SDU];
    float q=0.0f;
    for (int cu=0;cu<256;cu++){
      unsigned int u = rp[cu];
      float lo = __uint_as_float(u<<16);
      float hi = __uint_as_float(u & 0xffff0000u);
      q = fmaf(lo,lo,q); q = fmaf(hi,hi,q);
    }
    n1s[tid] = q;
  } else if (tid >= 64 && tid < 64+S_LEN){
    const unsigned int* rp = &h2s[(tid-64)*SDU];
    float q=0.0f;
    for (int cu=0;cu<256;cu++){
      unsigned int u = rp[cu];
      float lo = __uint_as_float(u<<16);
      float hi = __uint_as_float(u & 0xffff0000u);
      q = fmaf(lo,lo,q); q = fmaf(hi,hi,q);
    }
    n2s[tid-64] = q;
  }
  __syncthreads();
  if (tid < 225){
    const int gi = tid/15, gj = tid%15;
    float acc[4][4];
    #pragma unroll
    for (int a=0;a<4;a++)
      #pragma unroll
      for (int c=0;c<4;c++) acc[a][c]=0.0f;
    const unsigned int* r1[4]; const unsigned int* r2[4];
    #pragma unroll
    for (int a=0;a<4;a++){ r1[a]=&h1s[(gi*4+a)*SDU]; r2[a]=&h2s[(gj*4+a)*SDU]; }
    for (int cu=0;cu<256;cu++){
      float lo1[4],hi1[4],lo2[4],hi2[4];
      #pragma unroll
      for (int a=0;a<4;a++){
        unsigned int u = r1[a][cu];
        lo1[a]=__uint_as_float(u<<16); hi1[a]=__uint_as_float(u&0xffff0000u);
      }
      #pragma unroll
      for (int c=0;c<4;c++){
        unsigned int u = r2[c][cu];
        lo2[c]=__uint_as_float(u<<16); hi2[c]=__uint_as_float(u&0xffff0000u);
      }
      #pragma unroll
      for (int a=0;a<4;a++)
        #pragma unroll
        for (int c=0;c<4;c++)
          acc[a][c] = fmaf(lo1[a],lo2[c], fmaf(hi1[a],hi2[c], acc[a][c]));
    }
    float mn = 3.4e38f;
    #pragma unroll
    for (int a=0;a<4;a++)
      #pragma unroll
      for (int c=0;c<4;c++){
        float sq = n1s[gi*4+a] + n2s[gj*4+c] - 2.0f*acc[a][c];
        mn = fminf(mn, sqrtf(fmaxf(sq,0.0f)+1e-12f));
      }
    pooled[(size_t)b*225 + tid] = mn;
  }
}

// ---------------------------------------------------------------------------
// MLP kernels
// ---------------------------------------------------------------------------
__global__ __launch_bounds__(256) void k_mlp1(const float* __restrict__ pooled,
    const float* __restrict__ extra, const float* __restrict__ W1,
    const float* __restrict__ b1, float* __restrict__ y1)
{
  __shared__ __align__(16) float xs[232];
  const int b = blockIdx.x, tid = threadIdx.x;
  if (tid < 225) xs[tid] = pooled[(size_t)b*225 + tid];
  else if (tid < 232) xs[tid] = extra[(size_t)b*7 + (tid-225)];
  __syncthreads();
  #pragma unroll
  for (int q=0;q<4;q++){
    int n = tid + q*256;
    float acc = b1[n];
    const float4* wr = (const float4*)(W1 + (size_t)n*232);
    const float4* xr = (const float4*)xs;
    for (int k4=0;k4<58;k4++){
      float4 w = wr[k4]; float4 x = xr[k4];
      acc = fmaf(w.x,x.x, fmaf(w.y,x.y, fmaf(w.z,x.z, fmaf(w.w,x.w, acc))));
    }
    y1[(size_t)b*DMLP + n] = fmaxf(acc, 0.0f);
  }
}

__global__ __launch_bounds__(256) void k_mlp_bn(const float* __restrict__ y,
    const float* __restrict__ g, const float* __restrict__ be,
    float* __restrict__ scale, float* __restrict__ shift)
{
  const int n = blockIdx.x*256 + threadIdx.x;
  float s=0.0f, q=0.0f;
  for (int b=0;b<BATCH;b++){
    float v = y[(size_t)b*DMLP + n];
    s += v; q = fmaf(v,v,q);
  }
  float mean = s * (1.0f/256.0f);
  float var  = q * (1.0f/256.0f) - mean*mean;
  float sc = g[n] * rsqrtf(var + 1e-5f);
  scale[n] = sc;
  shift[n] = be[n] - mean*sc;
}

__global__ __launch_bounds__(256) void k_mlp2(const float* __restrict__ y1,
    const float* __restrict__ scale1, const float* __restrict__ shift1,
    const float* __restrict__ W2, const float* __restrict__ b2,
    float* __restrict__ y2)
{
  __shared__ __align__(16) float xs[4][DMLP];
  const int b0 = blockIdx.x*4, tid = threadIdx.x;
  for (int e=tid; e<4*DMLP; e+=256){
    int bb = e>>10, k = e&1023;
    xs[bb][k] = fmaf(y1[(size_t)(b0+bb)*DMLP + k], scale1[k], shift1[k]);
  }
  __syncthreads();
  #pragma unroll
  for (int q=0;q<4;q++){
    int n = tid + q*256;
    float a0=0.0f,a1=0.0f,a2=0.0f,a3=0.0f;
    const float4* wr = (const float4*)(W2 + (size_t)n*DMLP);
    for (int k4=0;k4<256;k4++){
      float4 w = wr[k4];
      float4 x0 = ((const float4*)xs[0])[k4];
      float4 x1 = ((const float4*)xs[1])[k4];
      float4 x2 = ((const float4*)xs[2])[k4];
      float4 x3 = ((const float4*)xs[3])[k4];
      a0 = fmaf(w.x,x0.x, fmaf(w.y,x0.y, fmaf(w.z,x0.z, fmaf(w.w,x0.w, a0))));
      a1 = fmaf(w.x,x1.x, fmaf(w.y,x1.y, fmaf(w.z,x1.z, fmaf(w.w,x1.w, a1))));
      a2 = fmaf(w.x,x2.x, fmaf(w.y,x2.y, fmaf(w.z,x2.z, fmaf(w.w,x2.w, a2))));
      a3 = fmaf(w.x,x3.x, fmaf(w.y,x3.y, fmaf(w.z,x3.z, fmaf(w.w,x3.w, a3))));
    }
    float bias = b2[n];
    y2[(size_t)(b0+0)*DMLP + n] = fmaxf(a0+bias, 0.0f);
    y2[(size_t)(b0+1)*DMLP + n] = fmaxf(a1+bias, 0.0f);
    y2[(size_t)(b0+2)*DMLP + n] = fmaxf(a2+bias, 0.0f);
    y2[(size_t)(b0+3)*DMLP + n] = fmaxf(a3+bias, 0.0f);
  }
}

__global__ __launch_bounds__(256) void k_mlp3(const float* __restrict__ y2,
    const float* __restrict__ scale2, const float* __restrict__ shift2,
    const float* __restrict__ W3, const float* __restrict__ b3,
    float* __restrict__ out)
{
  __shared__ float r0[256], r1[256];
  const int b = blockIdx.x, tid = threadIdx.x;
  float p0=0.0f, p1=0.0f;
  #pragma unroll
  for (int q=0;q<4;q++){
    int k = tid + q*256;
    float x = fmaf(y2[(size_t)b*DMLP + k], scale2[k], shift2[k]);
    p0 = fmaf(x, W3[k], p0);
    p1 = fmaf(x, W3[DMLP+k], p1);
  }
  r0[tid]=p0; r1[tid]=p1;
  __syncthreads();
  for (int s=128; s>0; s>>=1){
    if (tid<s){ r0[tid]+=r0[tid+s]; r1[tid]+=r1[tid+s]; }
    __syncthreads();
  }
  if (tid==0){
    float l0 = r0[0]+b3[0], l1 = r1[0]+b3[1];
    float m = fmaxf(l0,l1);
    float lse = m + logf(__expf(l0-m)+__expf(l1-m));
    out[b*2+0] = l0-lse;
    out[b*2+1] = l1-lse;
  }
}

// ---------------------------------------------------------------------------
extern "C" void kernel_launch(void* const* d_in, const int* in_sizes, int n_in,
                              void* d_out, int out_size, void* d_ws, size_t ws_size,
                              hipStream_t stream)
{
  (void)in_sizes; (void)n_in; (void)out_size; (void)ws_size;
  const float* embed = (const float*)d_in[0];
  const float* projW = (const float*)d_in[1];
  const float* projb = (const float*)d_in[2];
  const float* bn_g  = (const float*)d_in[3];
  const float* bn_b  = (const float*)d_in[4];
  const float* Wih   = (const float*)d_in[5];
  const float* Whh   = (const float*)d_in[6];
  const float* bih   = (const float*)d_in[7];
  const float* bhh   = (const float*)d_in[8];
  const float* W1    = (const float*)d_in[9];
  const float* b1    = (const float*)d_in[10];
  const float* g1    = (const float*)d_in[11];
  const float* be1   = (const float*)d_in[12];
  const float* W2    = (const float*)d_in[13];
  const float* b2    = (const float*)d_in[14];
  const float* g2    = (const float*)d_in[15];
  const float* be2   = (const float*)d_in[16];
  const float* W3    = (const float*)d_in[17];
  const float* b3    = (const float*)d_in[18];
  const float* extra = (const float*)d_in[19];
  const int*   s1    = (const int*)d_in[20];
  const int*   s2    = (const int*)d_in[21];
  float* out = (float*)d_out;

  float* ws = (float*)d_ws;
  size_t off = 0;
  float* P      = ws + off; off += (size_t)NROW*EMB;        // 9,216,000
  float* ps     = ws + off; off += (size_t)2*60*EMB;        // 36,000
  float* psq    = ws + off; off += (size_t)2*60*EMB;        // 36,000
  float* bnsc   = ws + off; off += 2*EMB;                   // 600
  float* bnsh   = ws + off; off += 2*EMB;                   // 600
  float* h0     = ws + off; off += (size_t)512*HID;         // 262,144
  float* cbuf   = ws + off; off += (size_t)512*HID;         // 262,144 (adjacent to h0 for one memset)
  float* h1b    = ws + off; off += (size_t)512*HID;
  __hip_bfloat16* Hout = (__hip_bfloat16*)(ws + off);
  off += (size_t)2*S_LEN*BATCH*HID/2;                       // bf16, 7,864,320 float-slots
  float* pooled = ws + off; off += (size_t)BATCH*225;
  float* y1     = ws + off; off += (size_t)BATCH*DMLP;
  float* y2     = ws + off; off += (size_t)BATCH*DMLP;
  float* sc1    = ws + off; off += DMLP;
  float* sh1    = ws + off; off += DMLP;
  float* sc2    = ws + off; off += DMLP;
  float* sh2    = ws + off; off += DMLP;
  // total ~74.1 MB of workspace

  // zero h0 and c (contiguous 2 MB); everything else is fully written before read
  hipMemsetAsync(h0, 0, (size_t)2*512*HID*sizeof(float), stream);

  k_embed_proj<<<dim3(NROW/64, 5), 256, 0, stream>>>(embed, projW, projb, s1, s2, P);
  k_bn_partial<<<dim3(60,2), 320, 0, stream>>>(P, ps, psq);
  k_bn_final<<<2, 320, 0, stream>>>(ps, psq, bn_g, bn_b, bnsc, bnsh);
  k_bn_apply<<<2048, 256, 0, stream>>>(P, bnsc, bnsh);

  for (int t=0; t<S_LEN; t++){
    const float* hin = (t & 1) ? h1b : h0;
    float*       hotp= (t & 1) ? h0  : h1b;
    k_lstm_step<<<dim3(16,32), 256, 0, stream>>>(P, Wih, Whh, bih, bhh,
                                                 hin, hotp, cbuf, Hout, t);
  }

  k_dist_pool<<<BATCH, 256, 0, stream>>>(Hout, pooled);
  k_mlp1<<<BATCH, 256, 0, stream>>>(pooled, extra, W1, b1, y1);
  k_mlp_bn<<<DMLP/256, 256, 0, stream>>>(y1, g1, be1, sc1, sh1);
  k_mlp2<<<BATCH/4, 256, 0, stream>>>(y1, sc1, sh1, W2, b2, y2);
  k_mlp_bn<<<DMLP/256, 256, 0, stream>>>(y2, g2, be2, sc2, sh2);
  k_mlp3<<<BATCH, 256, 0, stream>>>(y2, sc2, sh2, W3, b3, out);
}

// Round 2
// 1299.012 us; speedup vs baseline: 5.5449x; 5.5449x over previous
//
#include <hip/hip_runtime.h>
#include <hip/hip_bf16.h>

#define S_LEN 60
#define BATCH 256
#define EMB   300
#define EMBP  320              /* padded K for x-part (zero cols 300..319) */
#define HID   512
#define DMLP  1024
#define NROW  (2*S_LEN*BATCH)  /* 30720 */
#define RPS   (S_LEN*BATCH)    /* 15360 */

typedef __attribute__((ext_vector_type(8))) short short8v;
typedef __attribute__((ext_vector_type(4))) float f32x4;

static __device__ __forceinline__ float sigf(float x){
  return 1.0f/(1.0f+__expf(-x));
}
static __device__ __forceinline__ float tanh_fast(float x){
  x = fminf(fmaxf(x,-40.0f),40.0f);
  float a = __expf(2.0f*x);
  return (a-1.0f)/(a+1.0f);
}
static __device__ __forceinline__ unsigned short f2b(float v){
  __hip_bfloat16 h = __float2bfloat16(v);
  return *(unsigned short*)&h;
}
static __device__ __forceinline__ float b2f(unsigned short u){
  return __uint_as_float(((unsigned int)u)<<16);
}

// ---------------------------------------------------------------------------
// K1: embedding gather + projection GEMM -> bf16 P [30720][320] (zero-padded)
// ---------------------------------------------------------------------------
__global__ __launch_bounds__(256) void k_embed_proj(
    const float* __restrict__ embed, const float* __restrict__ projW,
    const float* __restrict__ projb, const int* __restrict__ s1,
    const int* __restrict__ s2, unsigned short* __restrict__ Pb)
{
  __shared__ float As[64][33];
  __shared__ float Bs[64][33];
  __shared__ int stok[64];
  const int m0 = blockIdx.x * 64;
  const int n0 = blockIdx.y * 64;
  const int tid = threadIdx.x;
  if (tid < 64){
    int r = m0 + tid;
    stok[tid] = (r < RPS) ? s1[r] : s2[r - RPS];
  }
  __syncthreads();
  const int tx = tid & 15, ty = tid >> 4;
  float acc[4][4];
  #pragma unroll
  for (int a=0;a<4;a++)
    #pragma unroll
    for (int b=0;b<4;b++) acc[a][b]=0.0f;

  for (int k0=0; k0<EMB; k0+=32){
    #pragma unroll
    for (int i=0;i<8;i++){
      int e = tid + i*256;
      int rl = e>>5, kl = e&31, kk = k0+kl;
      As[rl][kl] = (kk<EMB) ? embed[(size_t)stok[rl]*EMB + kk] : 0.0f;
      int nn = n0 + rl;
      Bs[rl][kl] = (nn<EMB && kk<EMB) ? projW[(size_t)nn*EMB + kk] : 0.0f;
    }
    __syncthreads();
    #pragma unroll
    for (int kk=0;kk<32;kk++){
      float a[4], w[4];
      #pragma unroll
      for (int rl=0;rl<4;rl++) a[rl] = As[ty*4+rl][kk];
      #pragma unroll
      for (int cj=0;cj<4;cj++) w[cj] = Bs[cj*16+tx][kk];
      #pragma unroll
      for (int rl=0;rl<4;rl++)
        #pragma unroll
        for (int cj=0;cj<4;cj++) acc[rl][cj] = fmaf(a[rl], w[cj], acc[rl][cj]);
    }
    __syncthreads();
  }
  #pragma unroll
  for (int rl=0;rl<4;rl++){
    int r = m0 + ty*4 + rl;
    #pragma unroll
    for (int cj=0;cj<4;cj++){
      int n = n0 + cj*16 + tx;   // n in [0,320)
      float val = (n < EMB) ? (acc[rl][cj] + projb[n]) : 0.0f;
      Pb[(size_t)r*EMBP + n] = f2b(val);
    }
  }
}

// ---------------------------------------------------------------------------
// K2: BN partial sums over bf16 P
// ---------------------------------------------------------------------------
__global__ __launch_bounds__(320) void k_bn_partial(const unsigned short* __restrict__ Pb,
    float* __restrict__ ps, float* __restrict__ psq)
{
  const int rb = blockIdx.x, sent = blockIdx.y, t = threadIdx.x;
  if (t >= EMB) return;
  const unsigned short* base = Pb + ((size_t)sent*RPS + (size_t)rb*256)*EMBP;
  float s=0.0f, q=0.0f;
  for (int r=0;r<256;r++){
    float v = b2f(base[(size_t)r*EMBP + t]);
    s += v; q = fmaf(v,v,q);
  }
  ps [(size_t)(sent*60+rb)*EMB + t] = s;
  psq[(size_t)(sent*60+rb)*EMB + t] = q;
}

__global__ __launch_bounds__(320) void k_bn_final(const float* __restrict__ ps,
    const float* __restrict__ psq, const float* __restrict__ g,
    const float* __restrict__ b, float* __restrict__ scale, float* __restrict__ shift)
{
  const int sent = blockIdx.x, t = threadIdx.x;
  if (t >= EMB) return;
  float s=0.0f, q=0.0f;
  for (int i=0;i<60;i++){
    s += ps [(size_t)(sent*60+i)*EMB + t];
    q += psq[(size_t)(sent*60+i)*EMB + t];
  }
  float mean = s * (1.0f/15360.0f);
  float var  = q * (1.0f/15360.0f) - mean*mean;
  float sc = g[t] * rsqrtf(var + 1e-5f);
  scale[sent*EMB+t] = sc;
  shift[sent*EMB+t] = b[t] - mean*sc;
}

// K3: apply BN in place on bf16 P (cols < 300; pads stay 0)
__global__ __launch_bounds__(256) void k_bn_apply(unsigned short* __restrict__ Pb,
    const float* __restrict__ scale, const float* __restrict__ shift)
{
  const int r = blockIdx.x*8 + (threadIdx.x>>5);
  const int c0 = threadIdx.x & 31;
  const int sent = (r >= RPS) ? 1 : 0;
  unsigned short* row = Pb + (size_t)r*EMBP;
  for (int c=c0; c<EMB; c+=32){
    float v = b2f(row[c]);
    v = fmaf(v, scale[sent*EMB+c], shift[sent*EMB+c]);
    row[c] = f2b(v);
  }
}

// ---------------------------------------------------------------------------
// K-conv: weights -> bf16 (Wih padded to K=320), bsum = bih+bhh
// ---------------------------------------------------------------------------
__global__ __launch_bounds__(256) void k_conv_weights(
    const float* __restrict__ Wih, const float* __restrict__ Whh,
    const float* __restrict__ bih, const float* __restrict__ bhh,
    unsigned short* __restrict__ Wihb, unsigned short* __restrict__ Whhb,
    float* __restrict__ bsum)
{
  const int tid = blockIdx.x*256 + threadIdx.x;
  const int stride = gridDim.x*256;
  for (int i=tid; i<2048*EMBP; i+=stride){
    int n = i/EMBP, k = i - n*EMBP;
    Wihb[i] = f2b((k<EMB) ? Wih[(size_t)n*EMB + k] : 0.0f);
  }
  for (int i=tid; i<2048*HID; i+=stride) Whhb[i] = f2b(Whh[i]);
  for (int i=tid; i<2048; i+=stride)     bsum[i] = bih[i]+bhh[i];
}

// ---------------------------------------------------------------------------
// K4: one LSTM step, bf16 MFMA.  Block = 64 rows x (4 gates x 16 hid cols).
// grid (8, 32), 512 threads (8 waves of 32rows x 16vcols). K = 320 + 512.
// Reg-staged LDS double buffer, 1 barrier per K-step.
// ---------------------------------------------------------------------------
__global__ __launch_bounds__(512) void k_lstm_mfma(
    const unsigned short* __restrict__ Pb,    // [30720][320]
    const unsigned short* __restrict__ Wihb,  // [2048][320]
    const unsigned short* __restrict__ Whhb,  // [2048][512]
    const float* __restrict__ bsum,           // [2048]
    const unsigned short* __restrict__ Hin,   // [512][512]
    unsigned short* __restrict__ Hnext,       // [512][512]
    float* __restrict__ cst,                  // [512][512]
    unsigned short* __restrict__ Hout,        // [2][60][256][512]
    int tstep)
{
  __shared__ __align__(16) char smem[20480];
  unsigned short* sA0 = (unsigned short*)(smem);
  unsigned short* sA1 = (unsigned short*)(smem + 5120);
  unsigned short* sW0 = (unsigned short*)(smem + 10240);
  unsigned short* sW1 = (unsigned short*)(smem + 15360);

  const int m0 = (int)blockIdx.x * 64;
  const int j0 = (int)blockIdx.y * 16;
  const int tid = threadIdx.x;
  const int lane = tid & 63, w = tid >> 6;
  const int wr = w >> 2, wc = w & 3;

  // staging role: threads 0..255 stage A (x/h rows), 256..511 stage W rows
  const bool isA = tid < 256;
  const int srow = (tid & 255) >> 2;    // 0..63
  const int sseg = tid & 3;             // 16B segment within 32-k window
  const int sent = m0 >> 8;
  const int wn = ((srow >> 4) * HID) + j0 + (srow & 15);   // gate*512 + j
  const unsigned short* Arow_x = Pb + ((size_t)(sent*S_LEN + tstep)*BATCH + (m0&255) + srow)*EMBP;
  const unsigned short* Arow_h = Hin + (size_t)(m0 + srow)*HID;
  const unsigned short* Wrow_x = Wihb + (size_t)wn*EMBP;
  const unsigned short* Wrow_h = Whhb + (size_t)wn*HID;

  f32x4 acc0 = {0.f,0.f,0.f,0.f}, acc1 = {0.f,0.f,0.f,0.f};

  // LDS tile: [64 rows][40 ushorts] (80B stride -> conflict-free b128)
  const int ldst = srow*40 + sseg*8;
  const int aoff0 = (wr*32 + (lane&15))*40 + (lane>>4)*8;
  const int aoff1 = aoff0 + 16*40;
  const int woff  = (wc*16 + (lane&15))*40 + (lane>>4)*8;

  // prologue: tile 0
  {
    const unsigned short* src = isA ? (Arow_x + 0 + sseg*8) : (Wrow_x + 0 + sseg*8);
    uint4 v = *(const uint4*)src;
    *(uint4*)((isA ? sA0 : sW0) + ldst) = v;
  }
  __syncthreads();

  for (int kk=0; kk<26; kk++){
    uint4 nv;
    if (kk < 25){
      int kn = kk+1;
      const unsigned short* src;
      if (isA) src = (kn < 10) ? (Arow_x + kn*32 + sseg*8) : (Arow_h + (kn-10)*32 + sseg*8);
      else     src = (kn < 10) ? (Wrow_x + kn*32 + sseg*8) : (Wrow_h + (kn-10)*32 + sseg*8);
      nv = *(const uint4*)src;
    }
    const unsigned short* A = (kk & 1) ? sA1 : sA0;
    const unsigned short* W = (kk & 1) ? sW1 : sW0;
    short8v af0 = *(const short8v*)(A + aoff0);
    short8v af1 = *(const short8v*)(A + aoff1);
    short8v wf  = *(const short8v*)(W + woff);
    acc0 = __builtin_amdgcn_mfma_f32_16x16x32_bf16(af0, wf, acc0, 0,0,0);
    acc1 = __builtin_amdgcn_mfma_f32_16x16x32_bf16(af1, wf, acc1, 0,0,0);
    if (kk < 25){
      unsigned short* dst = ((kk & 1) ? (isA ? sA0 : sW0) : (isA ? sA1 : sW1)) + ldst;
      *(uint4*)dst = nv;
    }
    __syncthreads();
  }

  // epilogue: z -> LDS f32 [64][66], then elementwise LSTM cell
  float* zs = (float*)smem;   // 64*66*4 = 16896 B <= 20480, staging dead
  #pragma unroll
  for (int v=0; v<4; v++){
    int r0 = wr*32 + (lane>>4)*4 + v;
    int cc = wc*16 + (lane&15);
    zs[r0*66 + cc]      = acc0[v];
    zs[(r0+16)*66 + cc] = acc1[v];
  }
  __syncthreads();
  #pragma unroll
  for (int q=0; q<2; q++){
    int cell = tid + q*512;          // 1024 cells = 64 rows x 16 hid
    int row = cell >> 4, jj = cell & 15;
    int r = m0 + row;
    int j = j0 + jj;
    float zi = zs[row*66 + jj]      + bsum[0*HID+j];
    float zf = zs[row*66 + 16+jj]   + bsum[1*HID+j];
    float zg = zs[row*66 + 32+jj]   + bsum[2*HID+j];
    float zo = zs[row*66 + 48+jj]   + bsum[3*HID+j];
    size_t ci = (size_t)r*HID + j;
    float cn = fmaf(sigf(zf), cst[ci], sigf(zi)*tanh_fast(zg));
    cst[ci] = cn;
    float hn = sigf(zo)*tanh_fast(cn);
    unsigned short hb = f2b(hn);
    Hnext[ci] = hb;
    int snt = r >> 8, b = r & 255;
    Hout[((size_t)(snt*S_LEN + tstep)*BATCH + b)*HID + j] = hb;
  }
}

// ---------------------------------------------------------------------------
// K5: fused pairwise-L2-distance + 15x15 min-pool (unchanged)
// ---------------------------------------------------------------------------
#define SDU 258
__global__ __launch_bounds__(256) void k_dist_pool(
    const unsigned short* __restrict__ Hout, float* __restrict__ pooled)
{
  __shared__ unsigned int h1s[S_LEN*SDU];
  __shared__ unsigned int h2s[S_LEN*SDU];
  __shared__ float n1s[S_LEN], n2s[S_LEN];
  const int b = blockIdx.x, tid = threadIdx.x;
  const unsigned int* H = (const unsigned int*)Hout;
  for (int e=tid; e<S_LEN*256; e+=256){
    int row = e>>8, cu = e&255;
    h1s[row*SDU+cu] = H[((size_t)(0*S_LEN+row)*BATCH + b)*256 + cu];
    h2s[row*SDU+cu] = H[((size_t)(1*S_LEN+row)*BATCH + b)*256 + cu];
  }
  __syncthreads();
  if (tid < S_LEN){
    const unsigned int* rp = &h1s[tid*SDU];
    float q=0.0f;
    for (int cu=0;cu<256;cu++){
      unsigned int u = rp[cu];
      float lo = __uint_as_float(u<<16);
      float hi = __uint_as_float(u & 0xffff0000u);
      q = fmaf(lo,lo,q); q = fmaf(hi,hi,q);
    }
    n1s[tid] = q;
  } else if (tid >= 64 && tid < 64+S_LEN){
    const unsigned int* rp = &h2s[(tid-64)*SDU];
    float q=0.0f;
    for (int cu=0;cu<256;cu++){
      unsigned int u = rp[cu];
      float lo = __uint_as_float(u<<16);
      float hi = __uint_as_float(u & 0xffff0000u);
      q = fmaf(lo,lo,q); q = fmaf(hi,hi,q);
    }
    n2s[tid-64] = q;
  }
  __syncthreads();
  if (tid < 225){
    const int gi = tid/15, gj = tid%15;
    float acc[4][4];
    #pragma unroll
    for (int a=0;a<4;a++)
      #pragma unroll
      for (int c=0;c<4;c++) acc[a][c]=0.0f;
    const unsigned int* r1[4]; const unsigned int* r2[4];
    #pragma unroll
    for (int a=0;a<4;a++){ r1[a]=&h1s[(gi*4+a)*SDU]; r2[a]=&h2s[(gj*4+a)*SDU]; }
    for (int cu=0;cu<256;cu++){
      float lo1[4],hi1[4],lo2[4],hi2[4];
      #pragma unroll
      for (int a=0;a<4;a++){
        unsigned int u = r1[a][cu];
        lo1[a]=__uint_as_float(u<<16); hi1[a]=__uint_as_float(u&0xffff0000u);
      }
      #pragma unroll
      for (int c=0;c<4;c++){
        unsigned int u = r2[c][cu];
        lo2[c]=__uint_as_float(u<<16); hi2[c]=__uint_as_float(u&0xffff0000u);
      }
      #pragma unroll
      for (int a=0;a<4;a++)
        #pragma unroll
        for (int c=0;c<4;c++)
          acc[a][c] = fmaf(lo1[a],lo2[c], fmaf(hi1[a],hi2[c], acc[a][c]));
    }
    float mn = 3.4e38f;
    #pragma unroll
    for (int a=0;a<4;a++)
      #pragma unroll
      for (int c=0;c<4;c++){
        float sq = n1s[gi*4+a] + n2s[gj*4+c] - 2.0f*acc[a][c];
        mn = fminf(mn, sqrtf(fmaxf(sq,0.0f)+1e-12f));
      }
    pooled[(size_t)b*225 + tid] = mn;
  }
}

// ---------------------------------------------------------------------------
// MLP kernels (unchanged)
// ---------------------------------------------------------------------------
__global__ __launch_bounds__(256) void k_mlp1(const float* __restrict__ pooled,
    const float* __restrict__ extra, const float* __restrict__ W1,
    const float* __restrict__ b1, float* __restrict__ y1)
{
  __shared__ __align__(16) float xs[232];
  const int b = blockIdx.x, tid = threadIdx.x;
  if (tid < 225) xs[tid] = pooled[(size_t)b*225 + tid];
  else if (tid < 232) xs[tid] = extra[(size_t)b*7 + (tid-225)];
  __syncthreads();
  #pragma unroll
  for (int q=0;q<4;q++){
    int n = tid + q*256;
    float acc = b1[n];
    const float4* wr = (const float4*)(W1 + (size_t)n*232);
    const float4* xr = (const float4*)xs;
    for (int k4=0;k4<58;k4++){
      float4 w = wr[k4]; float4 x = xr[k4];
      acc = fmaf(w.x,x.x, fmaf(w.y,x.y, fmaf(w.z,x.z, fmaf(w.w,x.w, acc))));
    }
    y1[(size_t)b*DMLP + n] = fmaxf(acc, 0.0f);
  }
}

__global__ __launch_bounds__(256) void k_mlp_bn(const float* __restrict__ y,
    const float* __restrict__ g, const float* __restrict__ be,
    float* __restrict__ scale, float* __restrict__ shift)
{
  const int n = blockIdx.x*256 + threadIdx.x;
  float s=0.0f, q=0.0f;
  for (int b=0;b<BATCH;b++){
    float v = y[(size_t)b*DMLP + n];
    s += v; q = fmaf(v,v,q);
  }
  float mean = s * (1.0f/256.0f);
  float var  = q * (1.0f/256.0f) - mean*mean;
  float sc = g[n] * rsqrtf(var + 1e-5f);
  scale[n] = sc;
  shift[n] = be[n] - mean*sc;
}

__global__ __launch_bounds__(256) void k_mlp2(const float* __restrict__ y1,
    const float* __restrict__ scale1, const float* __restrict__ shift1,
    const float* __restrict__ W2, const float* __restrict__ b2,
    float* __restrict__ y2)
{
  __shared__ __align__(16) float xs[4][DMLP];
  const int b0 = blockIdx.x*4, tid = threadIdx.x;
  for (int e=tid; e<4*DMLP; e+=256){
    int bb = e>>10, k = e&1023;
    xs[bb][k] = fmaf(y1[(size_t)(b0+bb)*DMLP + k], scale1[k], shift1[k]);
  }
  __syncthreads();
  #pragma unroll
  for (int q=0;q<4;q++){
    int n = tid + q*256;
    float a0=0.0f,a1=0.0f,a2=0.0f,a3=0.0f;
    const float4* wr = (const float4*)(W2 + (size_t)n*DMLP);
    for (int k4=0;k4<256;k4++){
      float4 w = wr[k4];
      float4 x0 = ((const float4*)xs[0])[k4];
      float4 x1 = ((const float4*)xs[1])[k4];
      float4 x2 = ((const float4*)xs[2])[k4];
      float4 x3 = ((const float4*)xs[3])[k4];
      a0 = fmaf(w.x,x0.x, fmaf(w.y,x0.y, fmaf(w.z,x0.z, fmaf(w.w,x0.w, a0))));
      a1 = fmaf(w.x,x1.x, fmaf(w.y,x1.y, fmaf(w.z,x1.z, fmaf(w.w,x1.w, a1))));
      a2 = fmaf(w.x,x2.x, fmaf(w.y,x2.y, fmaf(w.z,x2.z, fmaf(w.w,x2.w, a2))));
      a3 = fmaf(w.x,x3.x, fmaf(w.y,x3.y, fmaf(w.z,x3.z, fmaf(w.w,x3.w, a3))));
    }
    float bias = b2[n];
    y2[(size_t)(b0+0)*DMLP + n] = fmaxf(a0+bias, 0.0f);
    y2[(size_t)(b0+1)*DMLP + n] = fmaxf(a1+bias, 0.0f);
    y2[(size_t)(b0+2)*DMLP + n] = fmaxf(a2+bias, 0.0f);
    y2[(size_t)(b0+3)*DMLP + n] = fmaxf(a3+bias, 0.0f);
  }
}

__global__ __launch_bounds__(256) void k_mlp3(const float* __restrict__ y2,
    const float* __restrict__ scale2, const float* __restrict__ shift2,
    const float* __restrict__ W3, const float* __restrict__ b3,
    float* __restrict__ out)
{
  __shared__ float r0[256], r1[256];
  const int b = blockIdx.x, tid = threadIdx.x;
  float p0=0.0f, p1=0.0f;
  #pragma unroll
  for (int q=0;q<4;q++){
    int k = tid + q*256;
    float x = fmaf(y2[(size_t)b*DMLP + k], scale2[k], shift2[k]);
    p0 = fmaf(x, W3[k], p0);
    p1 = fmaf(x, W3[DMLP+k], p1);
  }
  r0[tid]=p0; r1[tid]=p1;
  __syncthreads();
  for (int s=128; s>0; s>>=1){
    if (tid<s){ r0[tid]+=r0[tid+s]; r1[tid]+=r1[tid+s]; }
    __syncthreads();
  }
  if (tid==0){
    float l0 = r0[0]+b3[0], l1 = r1[0]+b3[1];
    float m = fmaxf(l0,l1);
    float lse = m + logf(__expf(l0-m)+__expf(l1-m));
    out[b*2+0] = l0-lse;
    out[b*2+1] = l1-lse;
  }
}

// ---------------------------------------------------------------------------
extern "C" void kernel_launch(void* const* d_in, const int* in_sizes, int n_in,
                              void* d_out, int out_size, void* d_ws, size_t ws_size,
                              hipStream_t stream)
{
  (void)in_sizes; (void)n_in; (void)out_size; (void)ws_size;
  const float* embed = (const float*)d_in[0];
  const float* projW = (const float*)d_in[1];
  const float* projb = (const float*)d_in[2];
  const float* bn_g  = (const float*)d_in[3];
  const float* bn_b  = (const float*)d_in[4];
  const float* Wih   = (const float*)d_in[5];
  const float* Whh   = (const float*)d_in[6];
  const float* bih   = (const float*)d_in[7];
  const float* bhh   = (const float*)d_in[8];
  const float* W1    = (const float*)d_in[9];
  const float* b1    = (const float*)d_in[10];
  const float* g1    = (const float*)d_in[11];
  const float* be1   = (const float*)d_in[12];
  const float* W2    = (const float*)d_in[13];
  const float* b2    = (const float*)d_in[14];
  const float* g2    = (const float*)d_in[15];
  const float* be2   = (const float*)d_in[16];
  const float* W3    = (const float*)d_in[17];
  const float* b3    = (const float*)d_in[18];
  const float* extra = (const float*)d_in[19];
  const int*   s1    = (const int*)d_in[20];
  const int*   s2    = (const int*)d_in[21];
  float* out = (float*)d_out;

  float* ws = (float*)d_ws;
  size_t off = 0;
  float* ps   = ws + off; off += (size_t)2*60*EMB;                 // 36000
  float* psq  = ws + off; off += (size_t)2*60*EMB;                 // 36000
  float* bnsc = ws + off; off += 2*EMB;                            // 600
  float* bnsh = ws + off; off += 2*EMB;                            // 600
  float* bsum = ws + off; off += 2048;
  unsigned short* Pb   = (unsigned short*)(ws + off); off += (size_t)NROW*EMBP/2;   // 4,915,200
  unsigned short* Wihb = (unsigned short*)(ws + off); off += (size_t)2048*EMBP/2;   // 327,680
  unsigned short* Whhb = (unsigned short*)(ws + off); off += (size_t)2048*HID/2;    // 524,288
  float* cst = ws + off; off += (size_t)512*HID;                   // 262,144
  unsigned short* Hb0 = (unsigned short*)(ws + off); off += (size_t)512*HID/2;      // 131,072
  unsigned short* Hb1 = (unsigned short*)(ws + off); off += (size_t)512*HID/2;
  unsigned short* Hout = (unsigned short*)(ws + off); off += (size_t)2*S_LEN*BATCH*HID/2;
  float* pooled = ws + off; off += (size_t)BATCH*225;
  float* y1     = ws + off; off += (size_t)BATCH*DMLP;
  float* y2     = ws + off; off += (size_t)BATCH*DMLP;
  float* sc1    = ws + off; off += DMLP;
  float* sh1    = ws + off; off += DMLP;
  float* sc2    = ws + off; off += DMLP;
  float* sh2    = ws + off; off += DMLP;
  // total ~14.8M floats ~59 MB

  // zero c-state and Hb0 (contiguous)
  hipMemsetAsync(cst, 0, (size_t)(512*HID)*sizeof(float) + (size_t)(512*HID)*sizeof(unsigned short), stream);

  k_conv_weights<<<512, 256, 0, stream>>>(Wih, Whh, bih, bhh, Wihb, Whhb, bsum);
  k_embed_proj<<<dim3(NROW/64, 5), 256, 0, stream>>>(embed, projW, projb, s1, s2, Pb);
  k_bn_partial<<<dim3(60,2), 320, 0, stream>>>(Pb, ps, psq);
  k_bn_final<<<2, 320, 0, stream>>>(ps, psq, bn_g, bn_b, bnsc, bnsh);
  k_bn_apply<<<NROW/8, 256, 0, stream>>>(Pb, bnsc, bnsh);

  for (int t=0; t<S_LEN; t++){
    const unsigned short* hin = (t & 1) ? Hb1 : Hb0;
    unsigned short*      hnxt = (t & 1) ? Hb0 : Hb1;
    k_lstm_mfma<<<dim3(8,32), 512, 0, stream>>>(Pb, Wihb, Whhb, bsum,
                                                hin, hnxt, cst, Hout, t);
  }

  k_dist_pool<<<BATCH, 256, 0, stream>>>(Hout, pooled);
  k_mlp1<<<BATCH, 256, 0, stream>>>(pooled, extra, W1, b1, y1);
  k_mlp_bn<<<DMLP/256, 256, 0, stream>>>(y1, g1, be1, sc1, sh1);
  k_mlp2<<<BATCH/4, 256, 0, stream>>>(y1, sc1, sh1, W2, b2, y2);
  k_mlp_bn<<<DMLP/256, 256, 0, stream>>>(y2, g2, be2, sc2, sh2);
  k_mlp3<<<BATCH, 256, 0, stream>>>(y2, sc2, sh2, W3, b3, out);
}